// Round 8
// baseline (53.765 us; speedup 1.0000x reference)
//
#include <hip/hip_runtime.h>

// (B, S, H) = (8, 2048, 1024), fp32.
// Degenerate math: scores == 1/S exactly (softmax of a constant vector);
// context[b,h] == mean_s enc[b,s,h]; decoder_state cancels entirely.
// Lessons: R2 — grid.sync() ~200us on MI355X; R3 — contended atomics lose;
//          R4 — wide finalize: 19.5us; R5 — depth>occupancy; R6 — sched
//          barrier null -> residual is 2-dispatch overhead (~5-7us).
// R7: single dispatch. Producer blocks write partials + release a per-block
//     flag (magic = f(input) -> no initialization needed, correct for
//     garbage/poison/stale-flag states). 16 consumer-role blocks per batch
//     spin on their batch's flags then finalize a 64-h slice. All
//     cross-block data moves via agent-scope atomics (L2-bypass,
//     cross-XCD-safe). Deadlock-free: VGPR<=64 (launch_bounds 256,8) ->
//     capacity 2048 blocks >= 1024 grid, all co-resident from t=0.
#define BB 8
#define SS 2048
#define HH 1024
#define NCHUNK 128
#define CHUNK (SS / NCHUNK)      // 16
#define NBLK (BB * NCHUNK)       // 1024
#define FLAGS_OFF ((size_t)NBLK * HH)  // float offset of flag area in ws

__global__ void __launch_bounds__(256, 8)
att_onepass_kernel(const float* __restrict__ enc, float* __restrict__ ws,
                   float* __restrict__ out) {
    const int g = blockIdx.x;
    const int b = g >> 7;            // / NCHUNK
    const int c = g & (NCHUNK - 1);
    const int t = threadIdx.x;
    const float inv = 1.0f / SS;
    unsigned int* flags = (unsigned int*)(ws + FLAGS_OFF);
    const unsigned int magic = __float_as_uint(enc[0]) ^ 0xC001CAFEu;

    // ---- produce: sum 16 rows (two 8-deep independent load batches) ----
    const float4* p =
        (const float4*)(enc + ((size_t)b * SS + (size_t)c * CHUNK) * HH) + t;
    float4 acc;
    {
        float4 v[8];
        #pragma unroll
        for (int s = 0; s < 8; ++s) v[s] = p[(size_t)s * (HH / 4)];
        #pragma unroll
        for (int st = 4; st > 0; st >>= 1)
            #pragma unroll
            for (int s = 0; s < st; ++s) {
                v[s].x += v[s + st].x; v[s].y += v[s + st].y;
                v[s].z += v[s + st].z; v[s].w += v[s + st].w;
            }
        acc = v[0];
    }
    {
        float4 v[8];
        #pragma unroll
        for (int s = 0; s < 8; ++s) v[s] = p[(size_t)(8 + s) * (HH / 4)];
        #pragma unroll
        for (int st = 4; st > 0; st >>= 1)
            #pragma unroll
            for (int s = 0; s < st; ++s) {
                v[s].x += v[s + st].x; v[s].y += v[s + st].y;
                v[s].z += v[s + st].z; v[s].w += v[s + st].w;
            }
        acc.x += v[0].x; acc.y += v[0].y; acc.z += v[0].z; acc.w += v[0].w;
    }

    // partial store: agent-scope write-through (visible at coherence point)
    float* dst = ws + (size_t)g * HH + 4 * t;
    __hip_atomic_store(dst + 0, acc.x, __ATOMIC_RELAXED, __HIP_MEMORY_SCOPE_AGENT);
    __hip_atomic_store(dst + 1, acc.y, __ATOMIC_RELAXED, __HIP_MEMORY_SCOPE_AGENT);
    __hip_atomic_store(dst + 2, acc.z, __ATOMIC_RELAXED, __HIP_MEMORY_SCOPE_AGENT);
    __hip_atomic_store(dst + 3, acc.w, __ATOMIC_RELAXED, __HIP_MEMORY_SCOPE_AGENT);

    // scores: 16 per block (independent of the reduction)
    if (t < 16) out[BB * HH + g * 16 + t] = inv;

    __syncthreads();  // compiler drains vmcnt(0) for all threads before barrier
    if (t == 0)
        __hip_atomic_store(&flags[g], magic, __ATOMIC_RELEASE,
                           __HIP_MEMORY_SCOPE_AGENT);

    // ---- consumer role: blocks with (c & 7) == 0, 16 per batch ----
    if ((c & 7) != 0) return;
    const int hbase = (c >> 3) * 64;   // 16 slices x 64 h

    if (t < NCHUNK) {
        while (__hip_atomic_load(&flags[(b << 7) + t], __ATOMIC_RELAXED,
                                 __HIP_MEMORY_SCOPE_AGENT) != magic)
            __builtin_amdgcn_s_sleep(2);
    }
    __syncthreads();

    const int hl = t & 63;
    const int cq = t >> 6;             // 0..3, each sums 32 chunk-partials
    const float* q = ws + ((size_t)((b << 7) + cq * 32)) * HH + hbase + hl;
    float s = 0.f;
    #pragma unroll 8
    for (int i = 0; i < 32; ++i)
        s += __hip_atomic_load(q + (size_t)i * HH, __ATOMIC_RELAXED,
                               __HIP_MEMORY_SCOPE_AGENT);

    __shared__ float lds[4][64];
    lds[cq][hl] = s;
    __syncthreads();
    if (t < 64)
        out[b * HH + hbase + t] =
            (lds[0][t] + lds[1][t] + lds[2][t] + lds[3][t]) * inv;
}

// Fallback (workspace too small): direct full-column sums.
__global__ void __launch_bounds__(256)
att_direct_kernel(const float* __restrict__ enc, float* __restrict__ out) {
    int tid = blockIdx.x * blockDim.x + threadIdx.x;
    if (tid < BB * HH) {
        int b = tid >> 10;
        int h = tid & (HH - 1);
        const float* p = enc + (size_t)b * SS * HH + h;
        float acc = 0.f;
        for (int s = 0; s < SS; ++s) acc += p[(size_t)s * HH];
        out[tid] = acc * (1.0f / SS);
    } else if (tid < BB * HH + BB * SS) {
        out[tid] = 1.0f / SS;
    }
}

extern "C" void kernel_launch(void* const* d_in, const int* in_sizes, int n_in,
                              void* d_out, int out_size, void* d_ws, size_t ws_size,
                              hipStream_t stream) {
    const float* enc = (const float*)d_in[1];  // encoder_outputs (B,S,H)
    float* out = (float*)d_out;                // [context (B*H) | scores (B*S)]

    const size_t need = (FLAGS_OFF + NBLK) * sizeof(float);  // 4 MiB + 4 KiB
    if (d_ws != nullptr && ws_size >= need) {
        att_onepass_kernel<<<NBLK, 256, 0, stream>>>(enc, (float*)d_ws, out);
    } else {
        const int total_out = BB * HH + BB * SS;
        att_direct_kernel<<<(total_out + 255) / 256, 256, 0, stream>>>(enc, out);
    }
}